// Round 3
// baseline (778.146 us; speedup 1.0000x reference)
//
#include <hip/hip_runtime.h>
#include <stddef.h>

#define BS 8192
#define NNODE 25
#define TT 128
#define LOG2E 1.4426950408889634f

// Raw v_exp_f32: D = 2^x. (The name __exp2f collides with glibc math.h macros.)
__device__ __forceinline__ float ex2(float x) {
  return __builtin_amdgcn_exp2f(x);
}

// Static device buffers (no ws_size dependence). Fully rewritten every call.
__device__ float g_hf[NNODE * BS * 4];  // (i, b, d)
__device__ float g_hb[NNODE * BS * 4];

// Broadcast lane K of each quad (lanes 4q..4q+3) via DPP quad_perm.
template <int K>
__device__ __forceinline__ float bcast4(float v) {
  int s = __builtin_bit_cast(int, v);
  int r = __builtin_amdgcn_update_dpp(0, s, (K * 0x55), 0xF, 0xF, true);
  return __builtin_bit_cast(float, r);
}

// Swap lanes n <-> n^4 (cross-quad within each 8-lane group).
// BitMode offset = (xor<<10)|(or<<5)|and = (4<<10)|0x1F = 0x101F.
__device__ __forceinline__ float swz_xor4(float v) {
  int r = __builtin_amdgcn_ds_swizzle(__builtin_bit_cast(int, v), 0x101F);
  return __builtin_bit_cast(float, r);
}

// Pull value from lane ((lane&~7)|j) — group-of-8 broadcast, dynamic j.
// Robust to 32- vs 64-lane bpermute semantics since groups never cross halves.
__device__ __forceinline__ float bperm8(int byte_addr, float v) {
  int r = __builtin_amdgcn_ds_bpermute(byte_addr, __builtin_bit_cast(int, v));
  return __builtin_bit_cast(float, r);
}

// 8 lanes per (batch, dir) chain. sub = lane&7; half0 (sub<4) computes gate
// cols {d, 8+d} = (ig_d, og_d); half1 computes {4+d, 12+d} = (fg_d, cc_d).
// h/c state is mirrored on both halves so quad_perm broadcasts stay quad-local.
// grid (256, 2) x block 256 -> 2048 waves = 2 waves/SIMD.
__global__ __launch_bounds__(256, 2) void rnn_kernel(
    const float* __restrict__ x,
    const float* __restrict__ h0f, const float* __restrict__ c0f,
    const float* __restrict__ h0b, const float* __restrict__ c0b,
    const float* __restrict__ Wxf, const float* __restrict__ Whf,
    const float* __restrict__ Wnf, const float* __restrict__ bf,
    const float* __restrict__ Wxb, const float* __restrict__ Whb,
    const float* __restrict__ Wnb, const float* __restrict__ bb_) {
  const int tid = threadIdx.x;
  const int sub = tid & 7;
  const int d = sub & 3;
  const bool half1 = sub >= 4;
  const int b = blockIdx.x * 32 + (tid >> 3);
  const int dir = blockIdx.y;

  const float* Wx = dir ? Wxb : Wxf;
  const float* Wh = dir ? Whb : Whf;
  const float* Wn = dir ? Wnb : Wnf;
  const float* Bb = dir ? bb_ : bf;
  const float* h0 = dir ? h0b : h0f;
  const float* c0 = dir ? c0b : c0f;

  // Two gate-columns per lane. Neighbor rows: fwd [up,dn,lf,rt]=0,1,2,3;
  // bwd order is [up,dn,rt,lf] so lf-value uses row 3, rt-value row 2.
  const int col0 = (half1 ? 4 : 0) + d;
  float wx[2], wb[2], wh[2][4], wn[2][4];
#pragma unroll
  for (int g = 0; g < 2; ++g) {
    const int cc_ = col0 + g * 8;
    wx[g] = Wx[cc_];
    wb[g] = Bb[cc_];
#pragma unroll
    for (int k = 0; k < 4; ++k) wh[g][k] = Wh[k * 16 + cc_];
    wn[g][0] = Wn[0 * 16 + cc_];
    wn[g][1] = Wn[1 * 16 + cc_];
    wn[g][2] = Wn[(dir ? 3 : 2) * 16 + cc_];
    wn[g][3] = Wn[(dir ? 2 : 3) * 16 + cc_];
  }

  // Unified activation for eval2: y = sigma(scaled g2) -> v = a2*y + b2.
  // half0: sigma(og)  (s=-log2e, a=1, b=0); half1: tanh(cc) = 2*sigma(2x)-1.
  const float s2 = half1 ? (-2.0f * LOG2E) : (-LOG2E);
  const float a2 = half1 ? 2.0f : 1.0f;
  const float b2 = half1 ? -1.0f : 0.0f;

  float h[NNODE], c[NNODE];
#pragma unroll
  for (int i = 0; i < NNODE; ++i) {
    h[i] = h0[(i * BS + b) * 4 + d];  // mirrored: sub and sub+4 load same addr
    c[i] = c0[(i * BS + b) * 4 + d];
  }

  const float* xrow = x + (size_t)b * (NNODE * TT);
  const int bpb = ((tid & 63) & 0x38) << 2;  // bpermute byte-addr base

  for (int blk = 0; blk < 16; ++blk) {
    // Cooperative x load: lane sub holds logical step (blk*8+sub)'s value.
    const int t0 = dir ? (TT - 1 - blk * 8 - sub) : (blk * 8 + sub);
    float xq[NNODE];
#pragma unroll
    for (int i = 0; i < NNODE; ++i) xq[i] = xrow[i * TT + t0];

    for (int j = 0; j < 8; ++j) {
      const int bpa = bpb + (j << 2);
#pragma unroll
      for (int i = 0; i < NNODE; ++i) {
        const float xv = bperm8(bpa, xq[i]);
        // Own features (prev-t h[i]), quad-local broadcasts (mirrored state).
        const float f0 = bcast4<0>(h[i]);
        const float f1 = bcast4<1>(h[i]);
        const float f2 = bcast4<2>(h[i]);
        const float f3 = bcast4<3>(h[i]);
        // Neighbor feature-3. up/lf already updated this t; dn/rt prev-t.
        // lf/rt row-wrap is faithful to the reference.
        const float n0 = (i >= 5) ? bcast4<3>(h[i - 5]) : 0.0f;   // up
        const float n1 = (i < 20) ? bcast4<3>(h[i + 5]) : 0.0f;   // dn
        const float n2 = (i >= 1) ? bcast4<3>(h[i - 1]) : 0.0f;   // lf (serial dep)
        const float n3 = (i < 24) ? bcast4<3>(h[i + 1]) : 0.0f;   // rt

        float g1, g2;
        {
          float p = fmaf(xv, wx[0], wb[0]);
          p = fmaf(f0, wh[0][0], p);
          p = fmaf(f1, wh[0][1], p);
          p = fmaf(f2, wh[0][2], p);
          p = fmaf(f3, wh[0][3], p);
          float q = n0 * wn[0][0];
          q = fmaf(n1, wn[0][1], q);
          q = fmaf(n3, wn[0][3], q);
          g1 = fmaf(n2, wn[0][2], p + q);  // serial-dep term enters last
        }
        {
          float p = fmaf(xv, wx[1], wb[1]);
          p = fmaf(f0, wh[1][0], p);
          p = fmaf(f1, wh[1][1], p);
          p = fmaf(f2, wh[1][2], p);
          p = fmaf(f3, wh[1][3], p);
          float q = n0 * wn[1][0];
          q = fmaf(n1, wn[1][1], q);
          q = fmaf(n3, wn[1][3], q);
          g2 = fmaf(n2, wn[1][2], p + q);
        }
        // eval1: u = sigma(g1) uniform (half0: sig_i, half1: sig_f)
        const float u = __builtin_amdgcn_rcpf(1.0f + ex2(-LOG2E * g1));
        // eval2: v = a2*sigma(scaled g2)+b2 (half0: sig_o, half1: tanh_cc)
        const float y2 = __builtin_amdgcn_rcpf(1.0f + ex2(s2 * g2));
        const float v = fmaf(a2, y2, b2);
        // Cross-half swap, then canonicalize (cndmask).
        const float us = swz_xor4(u);
        const float vs = swz_xor4(v);
        const float sig_i = half1 ? us : u;
        const float sig_f = half1 ? u : us;
        const float sig_o = half1 ? vs : v;
        const float tnc = half1 ? v : vs;
        const float nc = fmaf(sig_f, c[i], sig_i * tnc);
        // eval3: tanh(nc) uniform, inline consts.
        const float w = fmaf(
            2.0f, __builtin_amdgcn_rcpf(1.0f + ex2(-2.0f * LOG2E * nc)), -1.0f);
        c[i] = nc;
        h[i] = sig_o * w;  // both halves compute identical h -> state mirrored
      }
    }
  }

  float* ho = dir ? g_hb : g_hf;
  if (!half1) {
#pragma unroll
    for (int i = 0; i < NNODE; ++i) ho[(i * BS + b) * 4 + d] = h[i];
  }
}

// H(b,200) -> sigmoid(H@Wff+bff) -> softmax(ff@Wout+bout).
__global__ __launch_bounds__(128) void ff_kernel(
    const float* __restrict__ Wff, const float* __restrict__ bff,
    const float* __restrict__ Wout, const float* __restrict__ bout,
    float* __restrict__ out) {
  __shared__ float Hs[8][200];
  __shared__ float ffs[8][129];
  const int tid = threadIdx.x;
  const int b0 = blockIdx.x * 8;

  for (int idx = tid; idx < 8 * 200; idx += 128) {
    const int bb = idx / 200;
    const int k = idx - bb * 200;
    const int i = k >> 3;
    const int dd = k & 7;
    const int b = b0 + bb;
    Hs[bb][k] = (dd < 4) ? g_hf[(i * BS + b) * 4 + dd]
                         : g_hb[(i * BS + b) * 4 + (dd - 4)];
  }
  __syncthreads();

  float acc[8];
  const float bv = bff[tid];
#pragma unroll
  for (int bb = 0; bb < 8; ++bb) acc[bb] = bv;
  for (int k = 0; k < 200; ++k) {
    const float w = Wff[k * 128 + tid];
#pragma unroll
    for (int bb = 0; bb < 8; ++bb) acc[bb] = fmaf(Hs[bb][k], w, acc[bb]);
  }
#pragma unroll
  for (int bb = 0; bb < 8; ++bb)
    ffs[bb][tid] = __builtin_amdgcn_rcpf(1.0f + ex2(-LOG2E * acc[bb]));
  __syncthreads();

  if (tid < 8) {
    float z0 = bout[0], z1 = bout[1];
    for (int n = 0; n < 128; ++n) {
      const float f = ffs[tid][n];
      z0 = fmaf(f, Wout[n * 2 + 0], z0);
      z1 = fmaf(f, Wout[n * 2 + 1], z1);
    }
    const float m = fmaxf(z0, z1);
    const float e0 = ex2(LOG2E * (z0 - m)), e1 = ex2(LOG2E * (z1 - m));
    const float s = __builtin_amdgcn_rcpf(e0 + e1);
    out[(size_t)(b0 + tid) * 2 + 0] = e0 * s;
    out[(size_t)(b0 + tid) * 2 + 1] = e1 * s;
  }
}

extern "C" void kernel_launch(void* const* d_in, const int* in_sizes, int n_in,
                              void* d_out, int out_size, void* d_ws, size_t ws_size,
                              hipStream_t stream) {
  (void)in_sizes; (void)n_in; (void)out_size; (void)d_ws; (void)ws_size;
  const float* x    = (const float*)d_in[0];
  const float* h0f  = (const float*)d_in[1];
  const float* c0f  = (const float*)d_in[2];
  const float* h0b  = (const float*)d_in[3];
  const float* c0b  = (const float*)d_in[4];
  const float* Wxf  = (const float*)d_in[5];
  const float* Whf  = (const float*)d_in[6];
  const float* Wnf  = (const float*)d_in[7];
  const float* bf   = (const float*)d_in[8];
  const float* Wxb  = (const float*)d_in[9];
  const float* Whb  = (const float*)d_in[10];
  const float* Wnb  = (const float*)d_in[11];
  const float* bb   = (const float*)d_in[12];
  const float* Wff  = (const float*)d_in[13];
  const float* bff  = (const float*)d_in[14];
  const float* Wout = (const float*)d_in[15];
  const float* bout = (const float*)d_in[16];
  float* out = (float*)d_out;

  rnn_kernel<<<dim3(256, 2), dim3(256), 0, stream>>>(
      x, h0f, c0f, h0b, c0b, Wxf, Whf, Wnf, bf, Wxb, Whb, Wnb, bb);
  ff_kernel<<<dim3(1024), dim3(128), 0, stream>>>(Wff, bff, Wout, bout, out);
}

// Round 4
// 590.912 us; speedup vs baseline: 1.3169x; 1.3169x over previous
//
#include <hip/hip_runtime.h>
#include <stddef.h>

#define BS 8192
#define NNODE 25
#define TT 128
#define LOG2E 1.4426950408889634f

typedef float v2f __attribute__((ext_vector_type(2)));

// Raw v_exp_f32 / v_rcp_f32. (__exp2f collides with glibc math.h macros.)
__device__ __forceinline__ float ex2(float x) { return __builtin_amdgcn_exp2f(x); }
__device__ __forceinline__ float rcp_(float x) { return __builtin_amdgcn_rcpf(x); }

// Static device buffers (no ws_size dependence). Fully rewritten every call.
__device__ float g_xT[(size_t)TT * NNODE * BS];  // (t, i, b)  ~105 MB
__device__ float g_hf[NNODE * BS * 4];           // (i, b, d)
__device__ float g_hb[NNODE * BS * 4];

// Broadcast lane K of each quad (lanes 4q..4q+3) via DPP quad_perm — 1 VALU op.
template <int K>
__device__ __forceinline__ float bcast4(float v) {
  int s = __builtin_bit_cast(int, v);
  int r = __builtin_amdgcn_update_dpp(0, s, (K * 0x55), 0xF, 0xF, true);
  return __builtin_bit_cast(float, r);
}

// Packed gate accumulate: A(ig',fg') B(og',cc') += splat(s) * w.
// float2 fma -> v_pk_fma_f32 on gfx950 (falls back to 2x v_fma_f32 if not).
__device__ __forceinline__ void acc2(v2f& A, v2f& B, float s, v2f wa, v2f wb) {
  v2f sv = {s, s};
  A = __builtin_elementwise_fma(sv, wa, A);
  B = __builtin_elementwise_fma(sv, wb, B);
}

// x (b, i, t) -> g_xT (t, i, b): 25 independent 8192x128 transposes, 32x32 tiles.
__global__ __launch_bounds__(256) void transpose_x(const float* __restrict__ x) {
  __shared__ float tile[32][33];
  const int i = blockIdx.z;
  const int b0 = blockIdx.x * 32;
  const int t0 = blockIdx.y * 32;
  const int tx = threadIdx.x;  // 0..31
  const int ty = threadIdx.y;  // 0..7
#pragma unroll
  for (int j = 0; j < 4; ++j) {
    int bl = ty + j * 8;
    tile[bl][tx] = x[((size_t)(b0 + bl) * NNODE + i) * TT + (t0 + tx)];
  }
  __syncthreads();
#pragma unroll
  for (int j = 0; j < 4; ++j) {
    int tl = ty + j * 8;
    g_xT[((size_t)(t0 + tl) * NNODE + i) * BS + (b0 + tx)] = tile[tx][tl];
  }
}

// Quad scheme (round-1 skeleton): 4 lanes per (batch, dir) chain; lane d owns
// feature d of all nodes' h/c and gate cols {d,4+d,8+d,12+d} = (ig,fg,og,cc).
// Gate prescale folded into weights: sigmoid cols x(-log2e), cc col x(2log2e),
// so accumulators feed v_exp_f32 directly. b3[] caches feature-3 broadcasts.
// grid (128, 2) x block 256 -> 1024 waves = 1 wave/SIMD (structural cap).
__global__ __launch_bounds__(256, 1) void rnn_kernel(
    const float* __restrict__ h0f, const float* __restrict__ c0f,
    const float* __restrict__ h0b, const float* __restrict__ c0b,
    const float* __restrict__ Wxf, const float* __restrict__ Whf,
    const float* __restrict__ Wnf, const float* __restrict__ bf,
    const float* __restrict__ Wxb, const float* __restrict__ Whb,
    const float* __restrict__ Wnb, const float* __restrict__ bb_) {
  const int dir = blockIdx.y;
  const int d = threadIdx.x & 3;
  const int b = blockIdx.x * 64 + (threadIdx.x >> 2);

  const float* Wx = dir ? Wxb : Wxf;
  const float* Wh = dir ? Whb : Whf;
  const float* Wn = dir ? Wnb : Wnf;
  const float* Bb = dir ? bb_ : bf;
  const float* h0 = dir ? h0b : h0f;
  const float* c0 = dir ? c0b : c0f;

  const int cI = d, cF = 4 + d, cO = 8 + d, cC = 12 + d;
  const float sS = -LOG2E, sC = 2.0f * LOG2E;

  // Packed prescaled weights. Input order k: 0=x, 1..4=h feats, 5..8=nb
  // [up,dn,lf,rt]. Neighbor rows: fwd [up,dn,lf,rt]=0,1,2,3; bwd order is
  // [up,dn,rt,lf] so lf-value uses row 3, rt-value row 2.
  v2f wA[9], wB[9];
  {
    wA[0] = v2f{sS * Wx[cI], sS * Wx[cF]};
    wB[0] = v2f{sS * Wx[cO], sC * Wx[cC]};
#pragma unroll
    for (int k = 0; k < 4; ++k) {
      wA[1 + k] = v2f{sS * Wh[k * 16 + cI], sS * Wh[k * 16 + cF]};
      wB[1 + k] = v2f{sS * Wh[k * 16 + cO], sC * Wh[k * 16 + cC]};
    }
    const int nrow[4] = {0, 1, dir ? 3 : 2, dir ? 2 : 3};
#pragma unroll
    for (int k = 0; k < 4; ++k) {
      wA[5 + k] = v2f{sS * Wn[nrow[k] * 16 + cI], sS * Wn[nrow[k] * 16 + cF]};
      wB[5 + k] = v2f{sS * Wn[nrow[k] * 16 + cO], sC * Wn[nrow[k] * 16 + cC]};
    }
  }
  const v2f bA = {sS * Bb[cI], sS * Bb[cF]};
  const v2f bB = {sS * Bb[cO], sC * Bb[cC]};

  float h[NNODE], c[NNODE], b3[NNODE];
#pragma unroll
  for (int i = 0; i < NNODE; ++i) {
    h[i] = h0[(i * BS + b) * 4 + d];
    c[i] = c0[(i * BS + b) * 4 + d];
    b3[i] = bcast4<3>(h[i]);
  }

  // fwd walks t=0..127, bwd walks t=127..0 (reversed sequence).
  const float* xbase = g_xT + ((size_t)(dir ? (TT - 1) : 0) * NNODE * BS);
  const ptrdiff_t xstep = dir ? -(ptrdiff_t)(NNODE * BS) : (ptrdiff_t)(NNODE * BS);

  for (int t = 0; t < TT; ++t) {
    // Issue all 25 x loads up front (coalesced via transposed layout).
    float xv[NNODE];
#pragma unroll
    for (int i = 0; i < NNODE; ++i) xv[i] = xbase[(size_t)i * BS + b];

#pragma unroll
    for (int i = 0; i < NNODE; ++i) {
      // Own features 0..2 via quad broadcast; feature 3 of everything via b3[].
      const float f0 = bcast4<0>(h[i]);
      const float f1 = bcast4<1>(h[i]);
      const float f2 = bcast4<2>(h[i]);

      v2f A = bA, B = bB;
      acc2(A, B, xv[i], wA[0], wB[0]);
      acc2(A, B, f0, wA[1], wB[1]);
      acc2(A, B, f1, wA[2], wB[2]);
      acc2(A, B, f2, wA[3], wB[3]);
      acc2(A, B, b3[i], wA[4], wB[4]);
      // Neighbors: up/lf already updated this t (j<i), dn/rt hold prev-t (j>i).
      // Out-of-range terms are exact zeros in the reference -> statically skip
      // (fma(0,w,acc)==acc bit-exact). lf/rt row-wrap is faithful.
      if (i >= 5) acc2(A, B, b3[i - 5], wA[5], wB[5]);   // up
      if (i < 20) acc2(A, B, b3[i + 5], wA[6], wB[6]);   // dn
      if (i >= 1) acc2(A, B, b3[i - 1], wA[7], wB[7]);   // lf (serial dep)
      if (i < 24) acc2(A, B, b3[i + 1], wA[8], wB[8]);   // rt

      // A = (-log2e*ig, -log2e*fg), B = (-log2e*og, 2log2e*cc)
      const float Ei = ex2(A.x);   // e^-ig
      const float Ef = ex2(A.y);   // e^-fg
      const float Eo = ex2(B.x);   // e^-og
      const float Ec = ex2(B.y);   // e^{2cc}
      // nc = c/(1+Ef) + (Ec-1)/((1+Ei)(Ec+1)), single rcp:
      const float Di = 1.0f + Ei;
      const float Df = 1.0f + Ef;
      const float P = Di * (Ec + 1.0f);
      const float num = fmaf(c[i], P, (Ec - 1.0f) * Df);
      const float nc = num * rcp_(Df * P);
      // h = sigmoid(og)*tanh(nc) = (1-En) / ((1+En)(1+Eo)), single rcp:
      const float En = ex2(-2.0f * LOG2E * nc);
      const float hn = (1.0f - En) * rcp_((1.0f + En) * (1.0f + Eo));
      c[i] = nc;
      h[i] = hn;
      b3[i] = bcast4<3>(hn);
    }
    xbase += xstep;
  }

  float* ho = dir ? g_hb : g_hf;
#pragma unroll
  for (int i = 0; i < NNODE; ++i) ho[(i * BS + b) * 4 + d] = h[i];
}

// H(b,200) -> sigmoid(H@Wff+bff) -> softmax(ff@Wout+bout).
__global__ __launch_bounds__(128) void ff_kernel(
    const float* __restrict__ Wff, const float* __restrict__ bff,
    const float* __restrict__ Wout, const float* __restrict__ bout,
    float* __restrict__ out) {
  __shared__ float Hs[8][200];
  __shared__ float ffs[8][129];
  const int tid = threadIdx.x;
  const int b0 = blockIdx.x * 8;

  for (int idx = tid; idx < 8 * 200; idx += 128) {
    const int bb = idx / 200;
    const int k = idx - bb * 200;
    const int i = k >> 3;
    const int dd = k & 7;
    const int b = b0 + bb;
    Hs[bb][k] = (dd < 4) ? g_hf[(i * BS + b) * 4 + dd]
                         : g_hb[(i * BS + b) * 4 + (dd - 4)];
  }
  __syncthreads();

  float acc[8];
  const float bv = bff[tid];
#pragma unroll
  for (int bb = 0; bb < 8; ++bb) acc[bb] = bv;
  for (int k = 0; k < 200; ++k) {
    const float w = Wff[k * 128 + tid];
#pragma unroll
    for (int bb = 0; bb < 8; ++bb) acc[bb] = fmaf(Hs[bb][k], w, acc[bb]);
  }
#pragma unroll
  for (int bb = 0; bb < 8; ++bb)
    ffs[bb][tid] = rcp_(1.0f + ex2(-LOG2E * acc[bb]));
  __syncthreads();

  if (tid < 8) {
    float z0 = bout[0], z1 = bout[1];
    for (int n = 0; n < 128; ++n) {
      const float f = ffs[tid][n];
      z0 = fmaf(f, Wout[n * 2 + 0], z0);
      z1 = fmaf(f, Wout[n * 2 + 1], z1);
    }
    const float m = fmaxf(z0, z1);
    const float e0 = ex2(LOG2E * (z0 - m)), e1 = ex2(LOG2E * (z1 - m));
    const float s = rcp_(e0 + e1);
    out[(size_t)(b0 + tid) * 2 + 0] = e0 * s;
    out[(size_t)(b0 + tid) * 2 + 1] = e1 * s;
  }
}

extern "C" void kernel_launch(void* const* d_in, const int* in_sizes, int n_in,
                              void* d_out, int out_size, void* d_ws, size_t ws_size,
                              hipStream_t stream) {
  (void)in_sizes; (void)n_in; (void)out_size; (void)d_ws; (void)ws_size;
  const float* x    = (const float*)d_in[0];
  const float* h0f  = (const float*)d_in[1];
  const float* c0f  = (const float*)d_in[2];
  const float* h0b  = (const float*)d_in[3];
  const float* c0b  = (const float*)d_in[4];
  const float* Wxf  = (const float*)d_in[5];
  const float* Whf  = (const float*)d_in[6];
  const float* Wnf  = (const float*)d_in[7];
  const float* bf   = (const float*)d_in[8];
  const float* Wxb  = (const float*)d_in[9];
  const float* Whb  = (const float*)d_in[10];
  const float* Wnb  = (const float*)d_in[11];
  const float* bb   = (const float*)d_in[12];
  const float* Wff  = (const float*)d_in[13];
  const float* bff  = (const float*)d_in[14];
  const float* Wout = (const float*)d_in[15];
  const float* bout = (const float*)d_in[16];
  float* out = (float*)d_out;

  transpose_x<<<dim3(256, 4, 25), dim3(32, 8), 0, stream>>>(x);
  rnn_kernel<<<dim3(128, 2), dim3(256), 0, stream>>>(
      h0f, c0f, h0b, c0b, Wxf, Whf, Wnf, bf, Wxb, Whb, Wnb, bb);
  ff_kernel<<<dim3(1024), dim3(128), 0, stream>>>(Wff, bff, Wout, bout, out);
}